// Round 1
// baseline (104.385 us; speedup 1.0000x reference)
//
#include <hip/hip_runtime.h>
#include <stdint.h>

#define T 16
#define NB 8
#define NROI 20000
#define NA 5
#define MM (NROI + NA)   // 20005
#define RPI 128
#define FGPI 32
#define SORTCAP 32768

// ---------------- threefry2x32 (JAX-exact, 20 rounds) ----------------
__device__ __forceinline__ void tf2x32(uint32_t k0, uint32_t k1,
                                       uint32_t x0, uint32_t x1,
                                       uint32_t& o0, uint32_t& o1) {
  uint32_t ks2 = k0 ^ k1 ^ 0x1BD11BDAu;
  x0 += k0; x1 += k1;
#define ROUND(r) { x0 += x1; x1 = (x1 << (r)) | (x1 >> (32 - (r))); x1 ^= x0; }
  ROUND(13) ROUND(15) ROUND(26) ROUND(6)
  x0 += k1; x1 += ks2 + 1u;
  ROUND(17) ROUND(29) ROUND(16) ROUND(24)
  x0 += ks2; x1 += k0 + 2u;
  ROUND(13) ROUND(15) ROUND(26) ROUND(6)
  x0 += k0; x1 += k1 + 3u;
  ROUND(17) ROUND(29) ROUND(16) ROUND(24)
  x0 += k1; x1 += ks2 + 4u;
  ROUND(13) ROUND(15) ROUND(26) ROUND(6)
  x0 += ks2; x1 += k0 + 5u;
#undef ROUND
  o0 = x0; o1 = x1;
}

// partitionable random_bits: counts are uint64 iota -> (hi=0, lo=i); 32-bit out = o0^o1
__device__ __forceinline__ uint32_t rbits32(uint32_t k0, uint32_t k1, uint32_t i) {
  uint32_t a, b; tf2x32(k0, k1, 0u, i, a, b); return a ^ b;
}
__device__ __forceinline__ float uni01(uint32_t bits) {
  return __uint_as_float((bits >> 9) | 0x3f800000u) - 1.0f;
}

// ---------------- kernel 1: init workspace + derive keys ----------------
__global__ __launch_bounds__(256) void k_init(uint64_t* __restrict__ fgk,
                                              uint64_t* __restrict__ bgk,
                                              int* __restrict__ counts,
                                              uint32_t* __restrict__ keys) {
  int tid = blockIdx.x * 256 + threadIdx.x;
  if (tid < NB * SORTCAP) { fgk[tid] = ~0ULL; bgk[tid] = ~0ULL; }
  if (tid < NB * 4) counts[tid] = ((tid & 3) >= 2) ? MM : 0;  // [fg_num, bg_num, min_nonfg, min_nonbg]
  if (tid < NB) {
    // root key(42) = (0,42); foldlike split: key_img = tf(root, 0, img); k_j = tf(key_img, 0, j)
    uint32_t r0, r1; tf2x32(0u, 42u, 0u, (uint32_t)tid, r0, r1);
    for (int j = 0; j < 4; ++j) {
      uint32_t a, b; tf2x32(r0, r1, 0u, (uint32_t)j, a, b);
      keys[(tid * 4 + j) * 2 + 0] = a;
      keys[(tid * 4 + j) * 2 + 1] = b;
    }
  }
}

// ---------------- kernel 2: per-roi max overlap, classify, append ----------------
__global__ __launch_bounds__(256) void k_overlap(const float* __restrict__ tubes,
                                                 const float* __restrict__ gtb,
                                                 unsigned char* __restrict__ asg,
                                                 uint64_t* __restrict__ fgk,
                                                 uint64_t* __restrict__ bgk,
                                                 int* __restrict__ counts,
                                                 const uint32_t* __restrict__ keys) {
  int img = blockIdx.y;
  __shared__ float g[NA][T][4];
  __shared__ float gar[NA][T];
  for (int i = threadIdx.x; i < NA * T; i += 256) {
    int a = i / T, t = i - a * T;
    const float* p = gtb + (((size_t)img * NA + a) * T + t) * 5;
    float x1 = p[0], y1 = p[1], x2 = p[2], y2 = p[3];
    g[a][t][0] = x1; g[a][t][1] = y1; g[a][t][2] = x2; g[a][t][3] = y2;
    gar[a][t] = (x2 - x1 + 1.0f) * (y2 - y1 + 1.0f);
  }
  __syncthreads();
  int n = blockIdx.x * 256 + threadIdx.x;
  if (n >= MM) return;

  float rx1 = 0.f, ry1 = 0.f, rx2 = 0.f, ry2 = 0.f, rar = 0.f;
  int sf, ef, ga = -1;
  if (n < NROI) {
    const float* p = tubes + ((size_t)img * NROI + n) * 7;
    rx1 = p[1]; ry1 = p[2]; rx2 = p[4]; ry2 = p[5];
    sf = (int)rintf(p[3]); ef = (int)rintf(p[6]);
    sf = max(sf, 0); ef = min(ef, T - 1);
    rar = (rx2 - rx1 + 1.0f) * (ry2 - ry1 + 1.0f);
  } else {
    ga = n - NROI; sf = 0; ef = T - 1;
  }

  float best = -1.0f; int barg = 0;
  for (int a = 0; a < NA; ++a) {
    float s = 0.0f;
    for (int t = sf; t <= ef; ++t) {
      float ex1, ey1, ex2, ey2, ar;
      if (ga < 0) { ex1 = rx1; ey1 = ry1; ex2 = rx2; ey2 = ry2; ar = rar; }
      else { ex1 = g[ga][t][0]; ey1 = g[ga][t][1]; ex2 = g[ga][t][2]; ey2 = g[ga][t][3]; ar = gar[ga][t]; }
      float iw = fmaxf(fminf(ex2, g[a][t][2]) - fmaxf(ex1, g[a][t][0]) + 1.0f, 0.0f);
      float ih = fmaxf(fminf(ey2, g[a][t][3]) - fmaxf(ey1, g[a][t][1]) + 1.0f, 0.0f);
      float inter = iw * ih;
      s += inter / (ar + gar[a][t] - inter);
    }
    float ov = s / 16.0f;
    if (ov > best) { best = ov; barg = a; }   // first-max == jnp.argmax
  }
  asg[(size_t)img * MM + n] = (unsigned char)barg;

  int base = img * 4;
  bool isfg = best >= 0.5f;
  bool isbg = (best < 0.5f) && (best >= 0.1f);
  if (isfg) {
    uint32_t m = rbits32(keys[(base + 0) * 2], keys[(base + 0) * 2 + 1], (uint32_t)n) >> 9;
    int pos = atomicAdd(&counts[base + 0], 1);
    fgk[(size_t)img * SORTCAP + pos] = ((uint64_t)m << 32) | (uint32_t)n;
  } else {
    atomicMin(&counts[base + 2], n);   // order_fg[fg_num] = smallest-index non-fg
  }
  if (isbg) {
    uint32_t m = rbits32(keys[(base + 1) * 2], keys[(base + 1) * 2 + 1], (uint32_t)n) >> 9;
    int pos = atomicAdd(&counts[base + 1], 1);
    bgk[(size_t)img * SORTCAP + pos] = ((uint64_t)m << 32) | (uint32_t)n;
  } else {
    atomicMin(&counts[base + 3], n);
  }
}

// ---------------- kernel 3: per-list bitonic sort (unique keys => stable argsort) ----------------
__global__ __launch_bounds__(1024) void k_sort(uint64_t* __restrict__ fgk,
                                               uint64_t* __restrict__ bgk,
                                               const int* __restrict__ counts) {
  int list = blockIdx.x;                 // 0..15 : (img<<1)|which
  int img = list >> 1;
  uint64_t* arr = ((list & 1) ? bgk : fgk) + (size_t)img * SORTCAP;
  int cnt = counts[img * 4 + (list & 1)];
  int n = 2; while (n < cnt) n <<= 1;    // pad region pre-filled with ~0ULL
  for (int k = 2; k <= n; k <<= 1) {
    for (int j = k >> 1; j > 0; j >>= 1) {
      for (int i = threadIdx.x; i < n; i += 1024) {
        int ixj = i ^ j;
        if (ixj > i) {
          uint64_t a = arr[i], b = arr[ixj];
          bool up = (i & k) == 0;
          if (up ? (a > b) : (a < b)) { arr[i] = b; arr[ixj] = a; }
        }
      }
      __syncthreads();
    }
  }
}

// ---------------- kernel 4: sample + gather + transform + write outputs ----------------
__global__ __launch_bounds__(128) void k_sample(const float* __restrict__ tubes,
                                                const float* __restrict__ gtb,
                                                const float* __restrict__ gta,
                                                const unsigned char* __restrict__ asg,
                                                const uint64_t* __restrict__ fgk,
                                                const uint64_t* __restrict__ bgk,
                                                const int* __restrict__ counts,
                                                const uint32_t* __restrict__ keys,
                                                float* __restrict__ out) {
  int img = blockIdx.x;
  int r = threadIdx.x;
  int base = img * 4;
  int fg_num = counts[base + 0], bg_num = counts[base + 1];
  int min_nonfg = counts[base + 2], min_nonbg = counts[base + 3];

  float u3 = uni01(rbits32(keys[(base + 2) * 2], keys[(base + 2) * 2 + 1], (uint32_t)r));
  float u4 = uni01(rbits32(keys[(base + 3) * 2], keys[(base + 3) * 2 + 1], (uint32_t)r));

  int fg_this = (bg_num > 0) ? min(FGPI, fg_num) : (fg_num > 0 ? RPI : 0);
  const uint64_t* fga = fgk + (size_t)img * SORTCAP;
  const uint64_t* bga = bgk + (size_t)img * SORTCAP;

  int fg_idx;
  if (bg_num > 0) {
    fg_idx = (int)(uint32_t)(fga[r] & 0xffffffffULL);   // order_fg[r]; only used for r<fg_this<=fg_num
  } else {
    int q = (int)(u3 * (float)max(fg_num, 1));          // f32 mul + trunc == .astype(int32)
    fg_idx = (q >= fg_num)
               ? ((fg_num >= MM) ? (int)(uint32_t)(fga[MM - 1] & 0xffffffffULL) : min_nonfg)
               : (int)(uint32_t)(fga[q] & 0xffffffffULL);
  }
  int qb = (int)(u4 * (float)max(bg_num, 1));
  int bg_idx = (qb >= bg_num)
                 ? ((bg_num >= MM) ? (int)(uint32_t)(bga[MM - 1] & 0xffffffffULL) : min_nonbg)
                 : (int)(uint32_t)(bga[qb] & 0xffffffffULL);

  bool is_fg = r < fg_this;
  int keep = is_fg ? fg_idx : bg_idx;
  int ak = asg[(size_t)img * MM + keep];
  float glab = gtb[(((size_t)img * NA + ak) * T + 0) * 5 + 4];  // labels constant+nonzero over frames
  float lab = is_fg ? glab : 0.0f;

  float* o_rois = out;
  float* o_tub = out + (size_t)NB * RPI * 65;
  float* o_lab = o_tub + (size_t)NB * RPI * 7;
  float* o_tgt = o_lab + (size_t)NB * RPI;
  float* o_in  = o_tgt + (size_t)NB * RPI * 64;
  float* o_ou  = o_in  + (size_t)NB * RPI * 64;
  size_t row = (size_t)img * RPI + r;
  float* pr = o_rois + row * 65;
  float* pt = o_tub + row * 7;
  float* pg = o_tgt + row * 64;
  float* pi = o_in + row * 64;
  float* po = o_ou + row * 64;

  pr[0] = (float)img;
  pt[0] = (float)img;
  if (keep < NROI) {
    const float* p = tubes + ((size_t)img * NROI + keep) * 7;
#pragma unroll
    for (int c = 1; c < 7; ++c) pt[c] = p[c];
  } else {
    const float* p = gta + ((size_t)img * NA + (keep - NROI)) * 7;
#pragma unroll
    for (int c = 1; c < 7; ++c) pt[c] = p[c - 1];  // [img, 0, x1min, y1min, 0, x2max, y2max]
  }
  o_lab[row] = lab;

  bool pos = lab > 0.0f;
  float posf = pos ? 1.0f : 0.0f;

  float tx1 = 0.f, ty1 = 0.f, tx2 = 0.f, ty2 = 0.f;
  int sf = 0, ef = -1;
  if (keep < NROI) {
    const float* p = tubes + ((size_t)img * NROI + keep) * 7;
    tx1 = p[1]; ty1 = p[2]; tx2 = p[4]; ty2 = p[5];
    sf = (int)rintf(p[3]); ef = (int)rintf(p[6]);
  }

#pragma unroll 4
  for (int t = 0; t < T; ++t) {
    float ex1, ey1, ex2, ey2;
    if (keep < NROI) {
      bool in = (t >= sf) && (t <= ef);
      ex1 = in ? tx1 : 0.0f; ey1 = in ? ty1 : 0.0f;
      ex2 = in ? tx2 : 0.0f; ey2 = in ? ty2 : 0.0f;
    } else {
      const float* p = gtb + (((size_t)img * NA + (keep - NROI)) * T + t) * 5;
      ex1 = p[0]; ey1 = p[1]; ex2 = p[2]; ey2 = p[3];
    }
    pr[1 + 4 * t + 0] = ex1; pr[1 + 4 * t + 1] = ey1;
    pr[1 + 4 * t + 2] = ex2; pr[1 + 4 * t + 3] = ey2;

    const float* gp = gtb + (((size_t)img * NA + ak) * T + t) * 5;
    float gx1 = gp[0], gy1 = gp[1], gx2 = gp[2], gy2 = gp[3];
    float ew = ex2 - ex1 + 1.0f, eh = ey2 - ey1 + 1.0f;
    float ecx = ex1 + 0.5f * ew, ecy = ey1 + 0.5f * eh;
    float gw = gx2 - gx1 + 1.0f, gh = gy2 - gy1 + 1.0f;
    float gcx = gx1 + 0.5f * gw, gcy = gy1 + 0.5f * gh;
    float t0 = ((gcx - ecx) / ew) / 0.1f;
    float t1 = ((gcy - ecy) / eh) / 0.1f;
    float t2 = logf(gw / ew) / 0.2f;
    float t3 = logf(gh / eh) / 0.2f;
    pg[4 * t + 0] = pos ? t0 : 0.0f;
    pg[4 * t + 1] = pos ? t1 : 0.0f;
    pg[4 * t + 2] = pos ? t2 : 0.0f;
    pg[4 * t + 3] = pos ? t3 : 0.0f;
    pi[4 * t + 0] = posf; pi[4 * t + 1] = posf; pi[4 * t + 2] = posf; pi[4 * t + 3] = posf;
    po[4 * t + 0] = posf; po[4 * t + 1] = posf; po[4 * t + 2] = posf; po[4 * t + 3] = posf;
  }
}

extern "C" void kernel_launch(void* const* d_in, const int* in_sizes, int n_in,
                              void* d_out, int out_size, void* d_ws, size_t ws_size,
                              hipStream_t stream) {
  const float* tubes = (const float*)d_in[0];       // [8][20000][7]
  const float* gtb   = (const float*)d_in[1];       // [8][5][16][5]
  const float* gta   = (const float*)d_in[2];       // [8][5][7]
  float* out = (float*)d_out;
  char* ws = (char*)d_ws;

  // workspace layout
  int*      counts = (int*)ws;                               // 32 ints @0
  uint32_t* keys   = (uint32_t*)(ws + 128);                  // 64 u32 @128..384
  unsigned char* asg = (unsigned char*)(ws + 384);           // 160040 B @384..160424
  uint64_t* fgk = (uint64_t*)(ws + 160424);                  // 8-aligned; 8*32768*8 B
  uint64_t* bgk = fgk + (size_t)NB * SORTCAP;
  // total = 160424 + 2*2097152 = 4,354,728 bytes

  k_init<<<(NB * SORTCAP + 255) / 256, 256, 0, stream>>>(fgk, bgk, counts, keys);
  dim3 gA((MM + 255) / 256, NB);
  k_overlap<<<gA, 256, 0, stream>>>(tubes, gtb, asg, fgk, bgk, counts, keys);
  k_sort<<<16, 1024, 0, stream>>>(fgk, bgk, counts);
  k_sample<<<NB, 128, 0, stream>>>(tubes, gtb, gta, asg, fgk, bgk, counts, keys, out);
}